// Round 2
// baseline (2451.837 us; speedup 1.0000x reference)
//
#include <hip/hip_runtime.h>
#include <hip/hip_bf16.h>

#define NPIECE 499
#define SEQN 500

typedef __attribute__((ext_vector_type(8))) short bf16x8;
typedef __attribute__((ext_vector_type(4))) short s16x4;
typedef __attribute__((ext_vector_type(4))) float f32x4;

__device__ inline short f2bf(float x) {
    union { float f; unsigned u; } v; v.f = x;
    unsigned r = v.u + 0x7FFFu + ((v.u >> 16) & 1u);   // RNE fp32->bf16
    return (short)(r >> 16);
}

__device__ inline float fast_tanh(float x) {
    float e = __expf(2.0f * x);
    return 1.0f - 2.0f * __builtin_amdgcn_rcpf(e + 1.0f);
}

// One block = one sample, 4 waves. 512 blocks -> 2 blocks/CU overlap.
__global__ void __launch_bounds__(256, 2)
cde_kernel(const float* __restrict__ times,
           const float* __restrict__ ca,  const float* __restrict__ cb,
           const float* __restrict__ c2c, const float* __restrict__ c3d,
           const float* __restrict__ initW, const float* __restrict__ initb,
           const float* __restrict__ W1,  const float* __restrict__ b1,
           const float* __restrict__ W2,  const float* __restrict__ b2,
           const float* __restrict__ linW, const float* __restrict__ linb,
           float* __restrict__ out)
{
    const int tid  = threadIdx.x;
    const int lane = tid & 63;
    const int wv   = tid >> 6;      // wave 0..3
    const int g    = lane >> 4;     // k-group 0..3
    const int col  = lane & 15;     // row (A) / col (B,D) within 16
    const int s    = blockIdx.x;    // sample

    __shared__ __align__(16) float tl[SEQN];      // times
    __shared__ __align__(16) float b2l[512];      // layer2 bias
    __shared__ __align__(16) float vbuf[4][128];  // per-wave v-preact
    __shared__ __align__(16) short hflat[128];    // h as bf16, k-linear
    __shared__ __align__(16) short zflat[64];     // z as bf16, k-linear
    __shared__ __align__(16) float zcur[64];
    __shared__ __align__(16) float dxb[2][3][8];  // [parity][slot][ch]

    for (int j = tid; j < SEQN; j += 256) tl[j] = times[j];
    for (int j = tid; j < 512; j += 256) b2l[j] = b2[j];

    // ---------------- weight fragments (bf16, registers) ---------------------
    // layer2: wave owns outputs o in [128*wv, 128*wv+128): 8 tiles x 4 chunks
    bf16x8 a2[8][4];
#pragma unroll
    for (int t = 0; t < 8; ++t) {
        int o = 128 * wv + 16 * t + col;
#pragma unroll
        for (int kk = 0; kk < 4; ++kk) {
            bf16x8 f;
#pragma unroll
            for (int e = 0; e < 8; ++e)
                f[e] = f2bf(W2[(32 * kk + 8 * g + e) * 512 + o]);
            a2[t][kk] = f;
        }
    }
    // layer1: wave owns h outputs [32*wv, 32*wv+32): 2 tiles x 2 chunks
    bf16x8 a1[2][2];
    float binit1[2][4];
#pragma unroll
    for (int t = 0; t < 2; ++t) {
        int o = 32 * wv + 16 * t + col;
#pragma unroll
        for (int kk = 0; kk < 2; ++kk) {
            bf16x8 f;
#pragma unroll
            for (int e = 0; e < 8; ++e)
                f[e] = f2bf(W1[(32 * kk + 8 * g + e) * 128 + o]);
            a1[t][kk] = f;
        }
#pragma unroll
        for (int r = 0; r < 4; ++r)
            binit1[t][r] = b1[32 * wv + 16 * t + 4 * g + r];
    }

    const size_t rowbase = (size_t)s * NPIECE * 8;

    __syncthreads();   // tl ready

    // ---------------- z0 + dx(step 0) ----------------------------------------
    if (tid < 64) {
        float z = initb[tid];
#pragma unroll
        for (int c = 0; c < 8; ++c)
            z += ca[rowbase + c] * initW[c * 64 + tid];
        zcur[tid] = z;
        zflat[tid] = f2bf(z);
    }
    const int pslot = tid >> 3, pch = tid & 7;
    if (tid < 24) {   // dx for step 0
        float t0n = tl[0], t1n = tl[1], hn = t1n - t0n;
        int p; float fr;
        if (pslot == 0)      { p = 0; fr = 0.0f; }
        else if (pslot == 1) { float th = t0n + 0.5f * hn; p = 0; fr = th - t0n; }
        else { float t3 = t0n + hn;
               if (t3 > t1n) { p = 1; fr = t3 - t1n; } else { p = 0; fr = t3 - t0n; } }
        size_t off = rowbase + (size_t)p * 8 + pch;
        dxb[0][pslot][pch] = cb[off] + (c2c[off] + c3d[off] * fr) * fr;
    }
    __syncthreads();

    // RK4 state: lane (lane&3)==0 of wave wv owns hid = 16*wv + lane/4
    float zreg = 0.f, zsreg = 0.f;
    if ((lane & 3) == 0) zreg = zcur[16 * wv + (lane >> 2)];

    for (int i = 0; i < NPIECE; ++i) {
        const float t0s = tl[i];
        const float hs  = tl[i + 1] - t0s;
        const int par = i & 1;

        // issue next step's coefficient loads (drained at stage 3)
        float pb = 0.f, pc = 0.f, pd = 0.f, pfr = 0.f;
        const bool pf = (i + 1 < NPIECE) && (tid < 24);
        if (pf) {
            int j = i + 1;
            float t0n = tl[j], t1n = tl[j + 1], hn = t1n - t0n;
            int p; float fr;
            if (pslot == 0)      { p = j - 1; fr = t0n - tl[j - 1]; }
            else if (pslot == 1) { float th = t0n + 0.5f * hn; p = j; fr = th - t0n; }
            else { float t3 = t0n + hn;
                   if (j < NPIECE - 1 && t3 > t1n) { p = j + 1; fr = t3 - t1n; }
                   else                            { p = j;     fr = t3 - t0n; } }
            size_t off = rowbase + (size_t)p * 8 + pch;
            pb = cb[off]; pc = c2c[off]; pd = c3d[off]; pfr = fr;
        }

#pragma unroll
        for (int st = 0; st < 4; ++st) {
            const int dsel = (st == 0) ? 0 : ((st == 3) ? 2 : 1);
            __syncthreads();   // barrier A: zflat (and dxb) ready

            if (st == 3 && pf)
                dxb[par ^ 1][pslot][pch] = pb + (pc + pd * pfr) * pfr;

            // ---- layer1: h = relu(z @ W1 + b1), wave computes its 32 h ----
            bf16x8 bz0 = *(const bf16x8*)&zflat[8 * g];
            bf16x8 bz1 = *(const bf16x8*)&zflat[32 + 8 * g];
            f32x4 h0 = {binit1[0][0], binit1[0][1], binit1[0][2], binit1[0][3]};
            f32x4 h1 = {binit1[1][0], binit1[1][1], binit1[1][2], binit1[1][3]};
            h0 = __builtin_amdgcn_mfma_f32_16x16x32_bf16(a1[0][0], bz0, h0, 0, 0, 0);
            h1 = __builtin_amdgcn_mfma_f32_16x16x32_bf16(a1[1][0], bz0, h1, 0, 0, 0);
            h0 = __builtin_amdgcn_mfma_f32_16x16x32_bf16(a1[0][1], bz1, h0, 0, 0, 0);
            h1 = __builtin_amdgcn_mfma_f32_16x16x32_bf16(a1[1][1], bz1, h1, 0, 0, 0);
            if (col == 0) {
                s16x4 w0, w1;
#pragma unroll
                for (int r = 0; r < 4; ++r) {
                    w0[r] = f2bf(fmaxf(h0[r], 0.f));
                    w1[r] = f2bf(fmaxf(h1[r], 0.f));
                }
                *(s16x4*)&hflat[32 * wv + 4 * g]      = w0;
                *(s16x4*)&hflat[32 * wv + 16 + 4 * g] = w1;
            }
            __syncthreads();   // barrier B: hflat ready

            // ---- layer2: v_pre = h @ W2 (bias deferred), wave's 128 outputs --
            bf16x8 bh0 = *(const bf16x8*)&hflat[8 * g];
            bf16x8 bh1 = *(const bf16x8*)&hflat[32 + 8 * g];
            bf16x8 bh2 = *(const bf16x8*)&hflat[64 + 8 * g];
            bf16x8 bh3 = *(const bf16x8*)&hflat[96 + 8 * g];
            f32x4 c[8];
#pragma unroll
            for (int t = 0; t < 8; ++t) c[t] = (f32x4){0.f, 0.f, 0.f, 0.f};
#pragma unroll
            for (int t = 0; t < 8; ++t)
                c[t] = __builtin_amdgcn_mfma_f32_16x16x32_bf16(a2[t][0], bh0, c[t], 0, 0, 0);
#pragma unroll
            for (int t = 0; t < 8; ++t)
                c[t] = __builtin_amdgcn_mfma_f32_16x16x32_bf16(a2[t][1], bh1, c[t], 0, 0, 0);
#pragma unroll
            for (int t = 0; t < 8; ++t)
                c[t] = __builtin_amdgcn_mfma_f32_16x16x32_bf16(a2[t][2], bh2, c[t], 0, 0, 0);
#pragma unroll
            for (int t = 0; t < 8; ++t)
                c[t] = __builtin_amdgcn_mfma_f32_16x16x32_bf16(a2[t][3], bh3, c[t], 0, 0, 0);

            if (col == 0) {
#pragma unroll
                for (int t = 0; t < 8; ++t)
                    *(f32x4*)&vbuf[wv][16 * t + 4 * g] = c[t];
            }
            // same-wave LDS RAW: DS pipe in-order per wave; fence the compiler
            asm volatile("s_waitcnt lgkmcnt(0)" ::: "memory");
            __builtin_amdgcn_wave_barrier();

            // ---- tanh + contraction: lane handles v[128*wv + 2*lane .. +1] ---
            {
                float2 vv = *(const float2*)&vbuf[wv][2 * lane];
                float2 bb = *(const float2*)&b2l[128 * wv + 2 * lane];
                float va = fast_tanh(vv.x + bb.x);
                float vb = fast_tanh(vv.y + bb.y);
                float2 dd = *(const float2*)&dxb[par][dsel][(2 * lane) & 7];
                float p = va * dd.x + vb * dd.y;
                p += __shfl_xor(p, 1);
                p += __shfl_xor(p, 2);
                if ((lane & 3) == 0) {
                    int hid = 16 * wv + (lane >> 2);
                    float k = p;
                    float zst;
                    if (st == 0)      { zsreg = k;           zst = zreg + 0.5f * hs * k; }
                    else if (st == 1) { zsreg += 2.f * k;    zst = zreg + 0.5f * hs * k; }
                    else if (st == 2) { zsreg += 2.f * k;    zst = zreg + hs * k; }
                    else              { zsreg += k;          zst = zreg + (hs / 6.f) * zsreg;
                                        zreg = zst;          zcur[hid] = zst; }
                    zflat[hid] = f2bf(zst);
                }
            }
        }
    }

    __syncthreads();
    // ---- readout: sigmoid(z @ lin_W + lin_b), wave 0 shuffle-reduce ----
    if (wv == 0) {
        float acc = zcur[lane] * linW[lane];
        acc += __shfl_xor(acc, 1);
        acc += __shfl_xor(acc, 2);
        acc += __shfl_xor(acc, 4);
        acc += __shfl_xor(acc, 8);
        acc += __shfl_xor(acc, 16);
        acc += __shfl_xor(acc, 32);
        if (lane == 0)
            out[s] = 1.0f / (1.0f + __expf(-(acc + linb[0])));
    }
}

extern "C" void kernel_launch(void* const* d_in, const int* in_sizes, int n_in,
                              void* d_out, int out_size, void* d_ws, size_t ws_size,
                              hipStream_t stream) {
    (void)in_sizes; (void)n_in; (void)d_ws; (void)ws_size; (void)out_size;
    const float* times = (const float*)d_in[0];
    const float* ca    = (const float*)d_in[1];
    const float* cb    = (const float*)d_in[2];
    const float* c2c   = (const float*)d_in[3];
    const float* c3d   = (const float*)d_in[4];
    const float* initW = (const float*)d_in[5];
    const float* initb = (const float*)d_in[6];
    const float* W1    = (const float*)d_in[7];
    const float* b1    = (const float*)d_in[8];
    const float* W2    = (const float*)d_in[9];
    const float* b2    = (const float*)d_in[10];
    const float* linW  = (const float*)d_in[11];
    const float* linb  = (const float*)d_in[12];
    cde_kernel<<<512, 256, 0, stream>>>(times, ca, cb, c2c, c3d, initW, initb,
                                        W1, b1, W2, b2, linW, linb, (float*)d_out);
}

// Round 3
// 2181.440 us; speedup vs baseline: 1.1240x; 1.1240x over previous
//
#include <hip/hip_runtime.h>

#define NPIECE 499
#define SEQN 500

typedef __attribute__((ext_vector_type(8))) short bf16x8;
typedef __attribute__((ext_vector_type(4))) short s16x4;
typedef __attribute__((ext_vector_type(4))) float f32x4;

__device__ inline short f2bf(float x) {
    union { float f; unsigned u; } v; v.f = x;
    unsigned r = v.u + 0x7FFFu + ((v.u >> 16) & 1u);   // RNE fp32->bf16
    return (short)(r >> 16);
}

__device__ inline float fast_tanh(float x) {
    float e = __expf(2.0f * x);
    return 1.0f - 2.0f * __builtin_amdgcn_rcpf(e + 1.0f);
}

// One block = 16 samples (full MFMA N), 8 waves. 32 blocks.
__global__ void __launch_bounds__(512, 2)
cde_kernel(const float* __restrict__ times,
           const float* __restrict__ ca,  const float* __restrict__ cb,
           const float* __restrict__ c2c, const float* __restrict__ c3d,
           const float* __restrict__ initW, const float* __restrict__ initb,
           const float* __restrict__ W1,  const float* __restrict__ b1,
           const float* __restrict__ W2,  const float* __restrict__ b2,
           const float* __restrict__ linW, const float* __restrict__ linb,
           float* __restrict__ out)
{
    const int tid  = threadIdx.x;
    const int lane = tid & 63;
    const int wv   = tid >> 6;      // wave 0..7
    const int g    = lane >> 4;     // 0..3
    const int col  = lane & 15;     // sample (B/D col), weight row (A)
    const int g0   = g & 1, g1 = g >> 1;
    const int s0   = blockIdx.x * 16;

    // zigzag bf16 activation layout: elem (k, sample) at [(k>>3)][sample][k&7]
    __shared__ __align__(16) float tl[SEQN];
    __shared__ __align__(16) short zflat[8][16][8];     // z  (K=64)
    __shared__ __align__(16) short hflat[16][16][8];    // h  (K=128)
    __shared__ __align__(16) float dxl[2][3][2][16][4]; // [par][slot][g0][sample][i&3]
    __shared__ __align__(16) float zinit[64][16];
    __shared__ __align__(16) float pred[8][16];

    for (int j = tid; j < SEQN; j += 512) tl[j] = times[j];

    // ---------------- weight fragments (bf16, registers) ---------------------
    // layer2: wave owns 4 output tiles (o = 16*(4wv+tt) + col), K=128 -> 4 chunks
    bf16x8 a2[4][4];
    float  b2f[4][4];
#pragma unroll
    for (int tt = 0; tt < 4; ++tt) {
        const int o = 16 * (4 * wv + tt) + col;
#pragma unroll
        for (int kk = 0; kk < 4; ++kk) {
            bf16x8 f;
#pragma unroll
            for (int e = 0; e < 8; ++e)
                f[e] = f2bf(W2[(32 * kk + 8 * g + e) * 512 + o]);
            a2[tt][kk] = f;
        }
#pragma unroll
        for (int r = 0; r < 4; ++r)
            b2f[tt][r] = b2[16 * (4 * wv + tt) + 4 * g + r];
    }
    // layer1: wave owns 1 output tile (h = 16wv + col), K=64 -> 2 chunks
    bf16x8 a1[2];
    float  b1f[4];
    {
        const int o = 16 * wv + col;
#pragma unroll
        for (int kk = 0; kk < 2; ++kk) {
            bf16x8 f;
#pragma unroll
            for (int e = 0; e < 8; ++e)
                f[e] = f2bf(W1[(32 * kk + 8 * g + e) * 128 + o]);
            a1[kk] = f;
        }
#pragma unroll
        for (int r = 0; r < 4; ++r) b1f[r] = b1[16 * wv + 4 * g + r];
    }

    __syncthreads();   // tl ready

    // ---------------- z0 = X(t0) @ init_W + init_b ---------------------------
#pragma unroll
    for (int v = 0; v < 2; ++v) {
        const int idx = tid * 2 + v, hid = idx >> 4, sm = idx & 15;
        float z = initb[hid];
#pragma unroll
        for (int c = 0; c < 8; ++c)
            z += ca[((size_t)(s0 + sm)) * (NPIECE * 8) + c] * initW[c * 64 + hid];
        zinit[hid][sm] = z;
        zflat[hid >> 3][sm][hid & 7] = f2bf(z);
    }
    // ---------------- dx for step 0 ------------------------------------------
    const int pslot = tid >> 7, prr = tid & 127, psm = prr >> 3, pch = prr & 7;
    const size_t prow = ((size_t)(s0 + psm)) * (NPIECE * 8);
    if (tid < 384) {
        float t0n = tl[0], t1n = tl[1], hn = t1n - t0n; int p; float fr;
        if (pslot == 0)      { p = 0; fr = 0.0f; }
        else if (pslot == 1) { p = 0; fr = (t0n + 0.5f * hn) - t0n; }
        else { float t3 = t0n + hn;
               if (t3 > t1n) { p = 1; fr = t3 - t1n; } else { p = 0; fr = t3 - t0n; } }
        const size_t off = prow + (size_t)p * 8 + pch;
        dxl[0][pslot][pch >> 2][psm][pch & 3] = cb[off] + (c2c[off] + c3d[off] * fr) * fr;
    }
    __syncthreads();

    // RK4 state: owner lanes (lane&31)<16 hold z[8wv+2tt+hi][col], tt=0..3
    const bool owner = ((lane & 31) < 16);
    const int hi = lane >> 5;
    float zreg[4], zs[4];
#pragma unroll
    for (int tt = 0; tt < 4; ++tt) {
        zs[tt] = 0.f;
        zreg[tt] = zinit[8 * wv + 2 * tt + hi][col];
    }

    for (int i = 0; i < NPIECE; ++i) {
        const float hs = tl[i + 1] - tl[i];
        const int par = i & 1;

        // register-prefetch next step's spline coefficients
        float pb = 0.f, pc = 0.f, pd = 0.f, pfr = 0.f;
        const bool pf = (i + 1 < NPIECE) && (tid < 384);
        if (pf) {
            const int j = i + 1;
            float t0n = tl[j], t1n = tl[j + 1], hn = t1n - t0n; int p; float fr;
            if (pslot == 0)      { p = j - 1; fr = t0n - tl[j - 1]; }
            else if (pslot == 1) { p = j; fr = (t0n + 0.5f * hn) - t0n; }
            else { float t3 = t0n + hn;
                   if (j < NPIECE - 1 && t3 > t1n) { p = j + 1; fr = t3 - t1n; }
                   else                            { p = j;     fr = t3 - t0n; } }
            const size_t off = prow + (size_t)p * 8 + pch;
            pb = cb[off]; pc = c2c[off]; pd = c3d[off]; pfr = fr;
        }

#pragma unroll
        for (int st = 0; st < 4; ++st) {
            const int dsel = (st == 0) ? 0 : ((st == 3) ? 2 : 1);
            __syncthreads();   // barrier A: zflat (and dxl[par]) ready

            if (st == 3 && pf)
                dxl[par ^ 1][pslot][pch >> 2][psm][pch & 3] = pb + (pc + pd * pfr) * pfr;

            // ---- layer1: h-tile = relu(z @ W1 + b1) ----
            bf16x8 bz0 = *(const bf16x8*)&zflat[g][col][0];
            bf16x8 bz1 = *(const bf16x8*)&zflat[4 + g][col][0];
            f32x4 ha = {b1f[0], b1f[1], b1f[2], b1f[3]};
            ha = __builtin_amdgcn_mfma_f32_16x16x32_bf16(a1[0], bz0, ha, 0, 0, 0);
            ha = __builtin_amdgcn_mfma_f32_16x16x32_bf16(a1[1], bz1, ha, 0, 0, 0);
            s16x4 wout;
#pragma unroll
            for (int r = 0; r < 4; ++r) wout[r] = f2bf(fmaxf(ha[r], 0.f));
            // h = 16wv + 4g + r -> [(2wv+g1)][col][4g0 + r]
            *(s16x4*)&hflat[2 * wv + g1][col][4 * g0] = wout;
            __syncthreads();   // barrier B: hflat ready

            // ---- layer2: 4 tiles, v = h @ W2 (bias added at tanh) ----
            bf16x8 bh[4];
#pragma unroll
            for (int c = 0; c < 4; ++c)
                bh[c] = *(const bf16x8*)&hflat[4 * c + g][col][0];
            f32x4 cc[4];
#pragma unroll
            for (int tt = 0; tt < 4; ++tt) cc[tt] = (f32x4){0.f, 0.f, 0.f, 0.f};
#pragma unroll
            for (int kk = 0; kk < 4; ++kk)
#pragma unroll
                for (int tt = 0; tt < 4; ++tt)
                    cc[tt] = __builtin_amdgcn_mfma_f32_16x16x32_bf16(a2[tt][kk], bh[kk], cc[tt], 0, 0, 0);

            // ---- in-register tanh + contraction ----
            // lane holds v[o = 16*(4wv+tt) + 4g + r][col]; i = o&7 = 4g0+r
            f32x4 dd = *(const f32x4*)&dxl[par][dsel][g0][col][0];
            float pt[4];
#pragma unroll
            for (int tt = 0; tt < 4; ++tt) {
                float s = 0.f;
#pragma unroll
                for (int r = 0; r < 4; ++r)
                    s += fast_tanh(cc[tt][r] + b2f[tt][r]) * dd[r];
                pt[tt] = s;
            }
#pragma unroll
            for (int tt = 0; tt < 4; ++tt)
                pt[tt] += __shfl_xor(pt[tt], 16);   // combine g0=0/1 -> full sum over i

            // ---- RK4 update (owner lanes), write next-stage z ----
            if (owner) {
#pragma unroll
                for (int tt = 0; tt < 4; ++tt) {
                    const float k = pt[tt];
                    float zst;
                    if (st == 0)      { zs[tt] = k;          zst = zreg[tt] + 0.5f * hs * k; }
                    else if (st == 1) { zs[tt] += 2.f * k;   zst = zreg[tt] + 0.5f * hs * k; }
                    else if (st == 2) { zs[tt] += 2.f * k;   zst = zreg[tt] + hs * k; }
                    else              { zs[tt] += k;         zst = zreg[tt] + (hs / 6.f) * zs[tt];
                                        zreg[tt] = zst; }
                    // hid = 8wv + 2tt + hi -> zflat[wv][col][2tt+hi]
                    zflat[wv][col][2 * tt + hi] = f2bf(zst);
                }
            }
        }
    }

    // ---------------- readout: sigmoid(z @ lin_W + lin_b) --------------------
    float p = 0.f;
#pragma unroll
    for (int tt = 0; tt < 4; ++tt) p += zreg[tt] * linW[8 * wv + 2 * tt + hi];
    p += __shfl_xor(p, 32);
    if (lane < 16) pred[wv][col] = p;
    __syncthreads();
    if (tid < 16) {
        float a = linb[0];
#pragma unroll
        for (int w = 0; w < 8; ++w) a += pred[w][tid];
        out[s0 + tid] = 1.0f / (1.0f + __expf(-a));
    }
}

extern "C" void kernel_launch(void* const* d_in, const int* in_sizes, int n_in,
                              void* d_out, int out_size, void* d_ws, size_t ws_size,
                              hipStream_t stream) {
    (void)in_sizes; (void)n_in; (void)d_ws; (void)ws_size; (void)out_size;
    const float* times = (const float*)d_in[0];
    const float* ca    = (const float*)d_in[1];
    const float* cb    = (const float*)d_in[2];
    const float* c2c   = (const float*)d_in[3];
    const float* c3d   = (const float*)d_in[4];
    const float* initW = (const float*)d_in[5];
    const float* initb = (const float*)d_in[6];
    const float* W1    = (const float*)d_in[7];
    const float* b1    = (const float*)d_in[8];
    const float* W2    = (const float*)d_in[9];
    const float* b2    = (const float*)d_in[10];
    const float* linW  = (const float*)d_in[11];
    const float* linb  = (const float*)d_in[12];
    cde_kernel<<<32, 512, 0, stream>>>(times, ca, cb, c2c, c3d, initW, initb,
                                       W1, b1, W2, b2, linW, linb, (float*)d_out);
}